// Round 7
// baseline (9656.464 us; speedup 1.0000x reference)
//
#include <hip/hip_runtime.h>
#include <hip/hip_bf16.h>

// ---------- types ----------
typedef __attribute__((ext_vector_type(8))) short  s16x8;
typedef __attribute__((ext_vector_type(4))) float  f32x4;
typedef __attribute__((ext_vector_type(4))) unsigned short u16x4;

#define B_  64
#define T_  1024
#define I_  512
#define H_  1024
#define O_  512
#define MT_ 65536   // B_*T_
#define BH_ 65536   // B_*H_ elements per h step

// scan decomposition: 4 row-groups x 16 col-slices (proven r5 layout)
#define RG_   4
#define CS_   16
#define WSLD  1048   // LDS row stride (shorts)

// ---------- helpers ----------
__device__ __forceinline__ unsigned short f2bf(float f) {
    unsigned u = __builtin_bit_cast(unsigned, f);
    u += 0x7FFFu + ((u >> 16) & 1u);
    return (unsigned short)(u >> 16);
}
__device__ __forceinline__ float bf2f(unsigned short h) {
    return __builtin_bit_cast(float, ((unsigned)h) << 16);
}
__device__ __forceinline__ void store_out(float* p, float v) { *p = v; }
__device__ __forceinline__ void store_out(unsigned short* p, float v) { *p = f2bf(v); }
__device__ __forceinline__ float to_f32(float v) { return v; }
__device__ __forceinline__ float to_f32(unsigned short v) { return bf2f(v); }
__device__ __forceinline__ unsigned umax_(unsigned a, unsigned b) { return a > b ? a : b; }

template<typename T> struct pre4;
template<> struct pre4<float>          { using t = f32x4; };
template<> struct pre4<unsigned short> { using t = u16x4; };

#define GL2LDS16(gp, lp) __builtin_amdgcn_global_load_lds( \
    (const __attribute__((address_space(1))) void*)(gp),   \
    (__attribute__((address_space(3))) void*)(lp), 16, 0, 0)

// ---------- conversion kernels ----------
__global__ void cvt_x(const float* __restrict__ src, unsigned short* __restrict__ dst, int n) {
    int stride = gridDim.x * blockDim.x * 4;
    for (int i = (blockIdx.x * blockDim.x + threadIdx.x) * 4; i < n; i += stride) {
        const float4 v = *(const float4*)(src + i);
        u16x4 o;
        o.x = f2bf(v.x); o.y = f2bf(v.y); o.z = f2bf(v.z); o.w = f2bf(v.w);
        *(u16x4*)(dst + i) = o;
    }
}

// dst[c][r] = bf16(src[row_off + r][c]);  src region [SR,SC] row-major -> dst [SC,SR]
__global__ void cvt_t(const float* __restrict__ src, unsigned short* __restrict__ dst,
                      int SR, int SC, int row_off) {
    __shared__ unsigned short tile[32][33];
    int c0 = blockIdx.x * 32, r0 = blockIdx.y * 32;
    int tx = threadIdx.x, ty = threadIdx.y;
    #pragma unroll
    for (int i = 0; i < 32; i += 8)
        tile[ty + i][tx] = f2bf(src[(size_t)(row_off + r0 + ty + i) * SC + c0 + tx]);
    __syncthreads();
    #pragma unroll
    for (int i = 0; i < 32; i += 8)
        dst[(size_t)(c0 + ty + i) * SR + r0 + tx] = tile[tx][ty + i];
}

// ---------- init: hist[0] = zeros, hist[1..T] = 0xFFFF sentinel ----------
// Separate kernel => end-of-dispatch writeback flushes these lines to the
// coherence point before the scan's sc0sc1 traffic reads them.
__global__ void init_hist(uint4* __restrict__ hist) {
    const uint4 z = {0u, 0u, 0u, 0u};
    const uint4 s = {~0u, ~0u, ~0u, ~0u};
    const size_t n16 = (size_t)(T_ + 1) * BH_ / 8;
    const size_t z16 = (size_t)BH_ / 8;
    size_t stride = (size_t)gridDim.x * blockDim.x;
    for (size_t i = (size_t)blockIdx.x * blockDim.x + threadIdx.x; i < n16; i += stride)
        hist[i] = (i < z16) ? z : s;
}

// ---------- generic bf16 MFMA GEMM: C[M,N] = act(A[M,K] @ BT[N,K]^T + bias) ----------
template<typename OutT, bool LRELU, bool SCATTER>
__global__ __launch_bounds__(256)
void gemm_bf16(const unsigned short* __restrict__ A,
               const unsigned short* __restrict__ BT,
               const float* __restrict__ bias,
               OutT* __restrict__ C, int M, int K, int N)
{
    __shared__ unsigned short As[4096]; // [128][32]
    __shared__ unsigned short Bs[4096]; // [128][32]
    const int tid = threadIdx.x, lane = tid & 63, wid = tid >> 6;
    const int wr = wid >> 1, wc = wid & 1;
    const int m0 = blockIdx.x * 128, n0 = blockIdx.y * 128;

    f32x4 acc[4][4] = {};

    const int c = wid * 2;
    const int srow = lane >> 2;
    const int scol = (lane & 3) * 8;
    const unsigned short* Ag0 = A  + (size_t)(m0 + c * 16 + srow) * K + scol;
    const unsigned short* Ag1 = A  + (size_t)(m0 + c * 16 + 16 + srow) * K + scol;
    const unsigned short* Bg0 = BT + (size_t)(n0 + c * 16 + srow) * K + scol;
    const unsigned short* Bg1 = BT + (size_t)(n0 + c * 16 + 16 + srow) * K + scol;

    for (int k0 = 0; k0 < K; k0 += 32) {
        __syncthreads();
        GL2LDS16(Ag0 + k0, As + c * 512);
        GL2LDS16(Ag1 + k0, As + (c + 1) * 512);
        GL2LDS16(Bg0 + k0, Bs + c * 512);
        GL2LDS16(Bg1 + k0, Bs + (c + 1) * 512);
        __syncthreads();

        s16x8 af[4], bfr[4];
        #pragma unroll
        for (int i = 0; i < 4; i++)
            af[i] = *(const s16x8*)(As + (wr * 64 + i * 16 + (lane & 15)) * 32 + (lane >> 4) * 8);
        #pragma unroll
        for (int j = 0; j < 4; j++)
            bfr[j] = *(const s16x8*)(Bs + (wc * 64 + j * 16 + (lane & 15)) * 32 + (lane >> 4) * 8);
        #pragma unroll
        for (int i = 0; i < 4; i++)
            #pragma unroll
            for (int j = 0; j < 4; j++)
                acc[i][j] = __builtin_amdgcn_mfma_f32_16x16x32_bf16(af[i], bfr[j], acc[i][j], 0, 0, 0);
    }

    #pragma unroll
    for (int j = 0; j < 4; j++) {
        const int n = n0 + wc * 64 + j * 16 + (lane & 15);
        const float bv = bias[n];
        #pragma unroll
        for (int i = 0; i < 4; i++) {
            #pragma unroll
            for (int r = 0; r < 4; r++) {
                const int m = m0 + wr * 64 + i * 16 + (lane >> 4) * 4 + r;
                if (m < M) {
                    float v = acc[i][j][r] + bv;
                    if (LRELU) v = v >= 0.f ? v : 0.01f * v;
                    size_t row = SCATTER ? (size_t)((m & (T_ - 1)) * B_ + (m >> 10)) : (size_t)m;
                    store_out(&C[row * N + n], v);
                }
            }
        }
    }
}

// ---------- scan v7: sentinel data-poll + drain-isolated pre prefetch ----------
// r5 structure, two fixes:
//  (1) pre prefetch issued AFTER discovery (behind the poll's memory clobber,
//      cannot hoist) into parity double-buffered regs consumed next step —
//      its HBM latency overlaps a full step instead of sitting inside the
//      step's only vmcnt(0) drain.
//  (2) s_sleep(1) backoff between poll retries (cut the r5 L3 request flood).
// Producer is pure fire-and-forget: exactly one vmcnt(0) per step (the poll).

#define HL(d, OFFSTR) asm volatile( \
    "global_load_dwordx4 %0, %1, off offset:" OFFSTR " sc0 sc1" \
    : "=v"(d) : "v"(hbase))

#define POLL32 do { \
    HL(hv[0],"0");     HL(hv[1],"64");    HL(hv[2],"128");   HL(hv[3],"192");   \
    HL(hv[4],"256");   HL(hv[5],"320");   HL(hv[6],"384");   HL(hv[7],"448");   \
    HL(hv[8],"512");   HL(hv[9],"576");   HL(hv[10],"640");  HL(hv[11],"704");  \
    HL(hv[12],"768");  HL(hv[13],"832");  HL(hv[14],"896");  HL(hv[15],"960");  \
    HL(hv[16],"1024"); HL(hv[17],"1088"); HL(hv[18],"1152"); HL(hv[19],"1216"); \
    HL(hv[20],"1280"); HL(hv[21],"1344"); HL(hv[22],"1408"); HL(hv[23],"1472"); \
    HL(hv[24],"1536"); HL(hv[25],"1600"); HL(hv[26],"1664"); HL(hv[27],"1728"); \
    HL(hv[28],"1792"); HL(hv[29],"1856"); HL(hv[30],"1920"); HL(hv[31],"1984"); \
    } while (0)

#define WAITV0 do { \
    asm volatile("s_waitcnt vmcnt(0)" ::: "memory"); \
    __builtin_amdgcn_sched_barrier(0); } while (0)

// One timestep. PVUSE: regs holding pre[S] (filled >=1 step ago, drained by this
// step's poll vmcnt(0)). PVFILL: issue pre[S+1] load here (post-discovery).
#define STEP(S, PVUSE, PVFILL) do { \
    const unsigned short* hc = hist + (size_t)(S) * BH_; \
    unsigned short*       hn = hist + (size_t)((S) + 1) * BH_; \
    const unsigned short* hbase = hc + (size_t)hrow * H_ + l4 * 8; \
    s16x8 hv[32]; \
    for (;;) { \
        POLL32; \
        WAITV0; \
        unsigned m = 0; \
        _Pragma("unroll") \
        for (int i = 0; i < 32; i++) { \
            uint4 wv = __builtin_bit_cast(uint4, hv[i]); \
            m = umax_(m, umax_(umax_(wv.x, wv.y), umax_(wv.z, wv.w))); \
        } \
        if (__all((int)(m != 0xFFFFFFFFu))) break; \
        __builtin_amdgcn_s_sleep(1); \
    } \
    { const int sn = ((S) + 1 < T_) ? (S) + 1 : (S); \
      PVFILL = *(const p4_t*)(pre + ((size_t)sn * B_ + hrow) * H_ + col0); } \
    f32x4 ac[4] = {}; \
    _Pragma("unroll") \
    for (int i = 0; i < 32; i++) { \
        s16x8 g = *(const s16x8*)(wsbase + i * 32); \
        ac[i & 3] = __builtin_amdgcn_mfma_f32_16x16x32_bf16(g, hv[i], ac[i & 3], 0, 0, 0); \
    } \
    f32x4 accv = (ac[0] + ac[1]) + (ac[2] + ac[3]); \
    u16x4 o; \
    _Pragma("unroll") \
    for (int r = 0; r < 4; r++) { \
        float v = accv[r] + to_f32(PVUSE[r]); \
        v = v >= 0.f ? v : 0.01f * v; \
        o[r] = f2bf(v); \
    } \
    { unsigned long long ov = __builtin_bit_cast(unsigned long long, o); \
      unsigned short* sp = hn + (size_t)hrow * H_ + col0; \
      asm volatile("global_store_dwordx2 %0, %1, off sc0 sc1" \
                   :: "v"(sp), "v"(ov) : "memory"); } \
  } while (0)

template<typename PreT>
__global__ __launch_bounds__(256, 1)
void rnn_scan7(const unsigned short* __restrict__ WbotT,
               const PreT* __restrict__ pre,       // [T][B][H] t-major
               unsigned short* __restrict__ hist)  // [T+1][B][H] bf16
{
    using p4_t = typename pre4<PreT>::t;
    __shared__ unsigned short Ws[64 * WSLD];
    const int tid = threadIdx.x, lane = tid & 63, w = tid >> 6;
    const int rg = (int)blockIdx.x >> 4;
    const int cs = (int)blockIdx.x & 15;
    const int row0 = rg * 16, n0 = cs * 64;

    for (int idx = tid; idx < 64 * 128; idx += 256) {
        int r = idx >> 7, ck = (idx & 127) * 8;
        *(s16x8*)(Ws + r * WSLD + ck) = *(const s16x8*)(WbotT + (size_t)(n0 + r) * H_ + ck);
    }
    __syncthreads();

    const int l15 = lane & 15, l4 = lane >> 4;
    const int hrow = row0 + l15;              // h row this thread reads AND writes
    const int col0 = n0 + w * 16 + l4 * 4;    // 4 consecutive output cols
    const unsigned short* wsbase = Ws + (size_t)(w * 16 + l15) * WSLD + l4 * 8;

    p4_t pvA, pvB;
    pvA = *(const p4_t*)(pre + (size_t)hrow * H_ + col0);   // pre[t=0]

    for (int t = 0; t < T_; t += 2) {
        STEP(t,     pvA, pvB);
        STEP(t + 1, pvB, pvA);
    }
}

// ---------- launch ----------
extern "C" void kernel_launch(void* const* d_in, const int* in_sizes, int n_in,
                              void* d_out, int out_size, void* d_ws, size_t ws_size,
                              hipStream_t stream)
{
    const float* x     = (const float*)d_in[0];
    const float* W_in  = (const float*)d_in[1];
    const float* b_in  = (const float*)d_in[2];
    const float* W_h   = (const float*)d_in[3];
    const float* b_h   = (const float*)d_in[4];
    const float* W_out = (const float*)d_in[5];
    const float* b_out = (const float*)d_in[6];
    float* out = (float*)d_out;

    char* ws = (char*)d_ws;
    size_t off = 0;
    auto alloc = [&](size_t bytes) { void* p = ws + off; off += (bytes + 255) & ~(size_t)255; return p; };

    unsigned short* Xb    = (unsigned short*)alloc((size_t)MT_ * I_ * 2);
    unsigned short* WinT  = (unsigned short*)alloc((size_t)H_ * I_ * 2);
    unsigned short* WtopT = (unsigned short*)alloc((size_t)H_ * H_ * 2);
    unsigned short* WbotT = (unsigned short*)alloc((size_t)H_ * H_ * 2);
    unsigned short* WoutT = (unsigned short*)alloc((size_t)O_ * H_ * 2);
    // hist [T+1][B][H] bf16; also serves as Abuf (GEMM1 out / GEMM2 in) — disjoint lifetimes
    unsigned short* hist  = (unsigned short*)alloc((size_t)(T_ + 1) * BH_ * 2);
    unsigned short* Abuf  = hist;
    void* pre = ws + off;
    const bool pre_f32 = (off + (size_t)MT_ * H_ * 4) <= ws_size;

    cvt_x<<<2048, 256, 0, stream>>>(x, Xb, MT_ * I_);
    dim3 tb(32, 8);
    cvt_t<<<dim3(H_ / 32, I_ / 32), tb, 0, stream>>>(W_in,  WinT,  I_, H_, 0);
    cvt_t<<<dim3(H_ / 32, H_ / 32), tb, 0, stream>>>(W_h,   WtopT, H_, H_, 0);
    cvt_t<<<dim3(H_ / 32, H_ / 32), tb, 0, stream>>>(W_h,   WbotT, H_, H_, H_);
    cvt_t<<<dim3(O_ / 32, H_ / 32), tb, 0, stream>>>(W_out, WoutT, H_, O_, 0);

    // GEMM1: A = lrelu(X @ W_in + b_in)   [MT, H] bf16
    gemm_bf16<unsigned short, true, false>
        <<<dim3(MT_ / 128, H_ / 128), 256, 0, stream>>>(Xb, WinT, b_in, Abuf, MT_, I_, H_);

    // GEMM2: pre = A @ Wtop + b_h   written t-major [T][B][H]
    if (pre_f32) {
        gemm_bf16<float, false, true>
            <<<dim3(MT_ / 128, H_ / 128), 256, 0, stream>>>(Abuf, WtopT, b_h, (float*)pre, MT_, H_, H_);
        init_hist<<<2048, 256, 0, stream>>>((uint4*)hist);
        rnn_scan7<float><<<RG_ * CS_, 256, 0, stream>>>(WbotT, (const float*)pre, hist);
    } else {
        gemm_bf16<unsigned short, false, true>
            <<<dim3(MT_ / 128, H_ / 128), 256, 0, stream>>>(Abuf, WtopT, b_h, (unsigned short*)pre, MT_, H_, H_);
        init_hist<<<2048, 256, 0, stream>>>((uint4*)hist);
        rnn_scan7<unsigned short><<<RG_ * CS_, 256, 0, stream>>>(WbotT, (const unsigned short*)pre, hist);
    }

    // final: out = h_final @ W_out + b_out   (h_final = hist[T])
    gemm_bf16<float, false, false>
        <<<dim3(1, O_ / 128), 256, 0, stream>>>(hist + (size_t)T_ * BH_, WoutT, b_out, out, B_, H_, O_);
}

// Round 8
// 6090.237 us; speedup vs baseline: 1.5856x; 1.5856x over previous
//
#include <hip/hip_runtime.h>
#include <hip/hip_bf16.h>

// ---------- types ----------
typedef __attribute__((ext_vector_type(8))) short  s16x8;
typedef __attribute__((ext_vector_type(4))) float  f32x4;
typedef __attribute__((ext_vector_type(4))) unsigned short u16x4;

#define B_  64
#define T_  1024
#define I_  512
#define H_  1024
#define O_  512
#define MT_ 65536   // B_*T_

// scan decomposition: 4 row-groups x 16 col-slices; 4 waves split K
#define RG_   4
#define CS_   16

// ---------- helpers ----------
__device__ __forceinline__ unsigned short f2bf(float f) {
    unsigned u = __builtin_bit_cast(unsigned, f);
    u += 0x7FFFu + ((u >> 16) & 1u);
    return (unsigned short)(u >> 16);
}
__device__ __forceinline__ float bf2f(unsigned short h) {
    return __builtin_bit_cast(float, ((unsigned)h) << 16);
}
__device__ __forceinline__ void store_out(float* p, float v) { *p = v; }
__device__ __forceinline__ void store_out(unsigned short* p, float v) { *p = f2bf(v); }
__device__ __forceinline__ float to_f32(float v) { return v; }
__device__ __forceinline__ float to_f32(unsigned short v) { return bf2f(v); }

template<typename T> struct pre4;
template<> struct pre4<float>          { using t = f32x4; };
template<> struct pre4<unsigned short> { using t = u16x4; };

// async pre loads (plain cached), pinned in issue order by asm volatile
__device__ __forceinline__ f32x4 pre_ld(const float* p) {
    f32x4 d; asm volatile("global_load_dwordx4 %0, %1, off" : "=v"(d) : "v"(p)); return d;
}
__device__ __forceinline__ u16x4 pre_ld(const unsigned short* p) {
    u16x4 d; asm volatile("global_load_dwordx2 %0, %1, off" : "=v"(d) : "v"(p)); return d;
}

#define GL2LDS16(gp, lp) __builtin_amdgcn_global_load_lds( \
    (const __attribute__((address_space(1))) void*)(gp),   \
    (__attribute__((address_space(3))) void*)(lp), 16, 0, 0)

// ---------- conversion kernels ----------
__global__ void cvt_x(const float* __restrict__ src, unsigned short* __restrict__ dst, int n) {
    int stride = gridDim.x * blockDim.x * 4;
    for (int i = (blockIdx.x * blockDim.x + threadIdx.x) * 4; i < n; i += stride) {
        const float4 v = *(const float4*)(src + i);
        u16x4 o;
        o.x = f2bf(v.x); o.y = f2bf(v.y); o.z = f2bf(v.z); o.w = f2bf(v.w);
        *(u16x4*)(dst + i) = o;
    }
}

// dst[c][r] = bf16(src[row_off + r][c]);  src region [SR,SC] row-major -> dst [SC,SR]
__global__ void cvt_t(const float* __restrict__ src, unsigned short* __restrict__ dst,
                      int SR, int SC, int row_off) {
    __shared__ unsigned short tile[32][33];
    int c0 = blockIdx.x * 32, r0 = blockIdx.y * 32;
    int tx = threadIdx.x, ty = threadIdx.y;
    #pragma unroll
    for (int i = 0; i < 32; i += 8)
        tile[ty + i][tx] = f2bf(src[(size_t)(row_off + r0 + ty + i) * SC + c0 + tx]);
    __syncthreads();
    #pragma unroll
    for (int i = 0; i < 32; i += 8)
        dst[(size_t)(c0 + ty + i) * SR + r0 + tx] = tile[tx][ty + i];
}

// ---------- generic bf16 MFMA GEMM: C[M,N] = act(A[M,K] @ BT[N,K]^T + bias) ----------
template<typename OutT, bool LRELU, bool SCATTER>
__global__ __launch_bounds__(256)
void gemm_bf16(const unsigned short* __restrict__ A,
               const unsigned short* __restrict__ BT,
               const float* __restrict__ bias,
               OutT* __restrict__ C, int M, int K, int N)
{
    __shared__ unsigned short As[4096]; // [128][32]
    __shared__ unsigned short Bs[4096]; // [128][32]
    const int tid = threadIdx.x, lane = tid & 63, wid = tid >> 6;
    const int wr = wid >> 1, wc = wid & 1;
    const int m0 = blockIdx.x * 128, n0 = blockIdx.y * 128;

    f32x4 acc[4][4] = {};

    const int c = wid * 2;
    const int srow = lane >> 2;
    const int scol = (lane & 3) * 8;
    const unsigned short* Ag0 = A  + (size_t)(m0 + c * 16 + srow) * K + scol;
    const unsigned short* Ag1 = A  + (size_t)(m0 + c * 16 + 16 + srow) * K + scol;
    const unsigned short* Bg0 = BT + (size_t)(n0 + c * 16 + srow) * K + scol;
    const unsigned short* Bg1 = BT + (size_t)(n0 + c * 16 + 16 + srow) * K + scol;

    for (int k0 = 0; k0 < K; k0 += 32) {
        __syncthreads();
        GL2LDS16(Ag0 + k0, As + c * 512);
        GL2LDS16(Ag1 + k0, As + (c + 1) * 512);
        GL2LDS16(Bg0 + k0, Bs + c * 512);
        GL2LDS16(Bg1 + k0, Bs + (c + 1) * 512);
        __syncthreads();

        s16x8 af[4], bfr[4];
        #pragma unroll
        for (int i = 0; i < 4; i++)
            af[i] = *(const s16x8*)(As + (wr * 64 + i * 16 + (lane & 15)) * 32 + (lane >> 4) * 8);
        #pragma unroll
        for (int j = 0; j < 4; j++)
            bfr[j] = *(const s16x8*)(Bs + (wc * 64 + j * 16 + (lane & 15)) * 32 + (lane >> 4) * 8);
        #pragma unroll
        for (int i = 0; i < 4; i++)
            #pragma unroll
            for (int j = 0; j < 4; j++)
                acc[i][j] = __builtin_amdgcn_mfma_f32_16x16x32_bf16(af[i], bfr[j], acc[i][j], 0, 0, 0);
    }

    #pragma unroll
    for (int j = 0; j < 4; j++) {
        const int n = n0 + wc * 64 + j * 16 + (lane & 15);
        const float bv = bias[n];
        #pragma unroll
        for (int i = 0; i < 4; i++) {
            #pragma unroll
            for (int r = 0; r < 4; r++) {
                const int m = m0 + wr * 64 + i * 16 + (lane >> 4) * 4 + r;
                if (m < M) {
                    float v = acc[i][j][r] + bv;
                    if (LRELU) v = v >= 0.f ? v : 0.01f * v;
                    size_t row = SCATTER ? (size_t)((m & (T_ - 1)) * B_ + (m >> 10)) : (size_t)m;
                    store_out(&C[row * N + n], v);
                }
            }
        }
    }
}

// ---------- scan v8: K-split waves, flag dataflow, swizzled Ws, LDS reduce ----------
// 64 blocks (4 rg x 16 cs) x 256 thr. Wave w loads only its k-quarter of the
// 16-row h stripe (8KB, global sc0sc1 -> regs, NO duplication: 2MB/step total).
// Each wave computes partial C (16 rows x 64 cols) vs swizzled LDS Ws; 4-way
// cross-wave reduce through padded LDS (one barrier); epilogue stores 8B/thread.
// Flag poll (r4 scheme) doubles as the intra-block barrier between steps.

#define HL8(d, OFFSTR) asm volatile( \
    "global_load_dwordx4 %0, %1, off offset:" OFFSTR " sc0 sc1" \
    : "=v"(d) : "v"(hbase))

#define STEP(S, PVUSE, PVFILL) do { \
    const unsigned short* hc = hbuf + (((S) & 1) << 16); \
    unsigned short*       hn = hbuf + ((((S) + 1) & 1) << 16); \
    if ((S) > 0) { \
        unsigned f; \
        do { \
            asm volatile("global_load_dword %0, %1, off sc0 sc1\n\t" \
                         "s_waitcnt vmcnt(0)" \
                         : "=v"(f) : "v"(fp) : "memory"); \
        } while (!__all((int)(f >= (unsigned)(S)))); \
    } \
    const unsigned short* hbase = hc + (size_t)hrow * H_ + w * 256 + l4 * 8; \
    s16x8 hv[8]; \
    HL8(hv[0], "0");   HL8(hv[1], "64");  HL8(hv[2], "128"); HL8(hv[3], "192"); \
    HL8(hv[4], "256"); HL8(hv[5], "320"); HL8(hv[6], "384"); HL8(hv[7], "448"); \
    { const int sn = ((S) + 1 < T_) ? (S) + 1 : (S); \
      PVFILL = pre_ld(pre + ((size_t)sn * B_ + hrow) * H_ + col0); } \
    asm volatile("s_waitcnt vmcnt(1)" ::: "memory"); \
    __builtin_amdgcn_sched_barrier(0); \
    f32x4 ac[4] = {}; \
    _Pragma("unroll") \
    for (int cg = 0; cg < 4; ++cg) { \
        const char* pE = wE + cg * 32768; \
        const char* pO = wO + cg * 32768; \
        _Pragma("unroll") \
        for (int j = 0; j < 8; ++j) { \
            s16x8 g = *(const s16x8*)(((j & 1) ? pO : pE) + j * 64); \
            ac[cg] = __builtin_amdgcn_mfma_f32_16x16x32_bf16(g, hv[j], ac[cg], 0, 0, 0); \
        } \
    } \
    { float* pw_ = pbuf + (w * 16 + l15) * 68 + l4 * 4; \
      *(f32x4*)(pw_ +  0) = ac[0]; \
      *(f32x4*)(pw_ + 16) = ac[1]; \
      *(f32x4*)(pw_ + 32) = ac[2]; \
      *(f32x4*)(pw_ + 48) = ac[3]; } \
    asm volatile("s_waitcnt lgkmcnt(0)" ::: "memory"); \
    __builtin_amdgcn_s_barrier(); \
    asm volatile("" ::: "memory"); \
    { const float* pr_ = pbuf + l15 * 68 + w * 16 + l4 * 4; \
      f32x4 s0 = *(const f32x4*)(pr_); \
      f32x4 s1 = *(const f32x4*)(pr_ + 1088); \
      f32x4 s2 = *(const f32x4*)(pr_ + 2176); \
      f32x4 s3 = *(const f32x4*)(pr_ + 3264); \
      f32x4 sm = (s0 + s1) + (s2 + s3); \
      u16x4 o; \
      _Pragma("unroll") \
      for (int r = 0; r < 4; r++) { \
          float v = sm[r] + to_f32(PVUSE[r]); \
          v = v >= 0.f ? v : 0.01f * v; \
          o[r] = f2bf(v); \
      } \
      unsigned long long ov = __builtin_bit_cast(unsigned long long, o); \
      unsigned short* sp = hn + (size_t)hrow * H_ + col0; \
      asm volatile("global_store_dwordx2 %0, %1, off sc0 sc1" \
                   :: "v"(sp), "v"(ov) : "memory"); } \
    asm volatile("s_waitcnt vmcnt(0)" ::: "memory"); \
    if (lane == 0) { \
        unsigned tv = (unsigned)((S) + 1); \
        asm volatile("global_store_dword %0, %1, off sc0 sc1" \
                     :: "v"(myflag), "v"(tv) : "memory"); \
    } \
  } while (0)

template<typename PreT>
__global__ __launch_bounds__(256, 1)
void rnn_scan8(const unsigned short* __restrict__ WbotT,
               const PreT* __restrict__ pre,      // [T][B][H] t-major
               unsigned short* __restrict__ hbuf, // [2][B][H] bf16
               unsigned* __restrict__ flags)      // [RG_][64] u32
{
    using p4_t = typename pre4<PreT>::t;
    __shared__ unsigned short Ws[64 * 1024];      // 128KiB, XOR-swizzled rows
    __shared__ float pbuf[4 * 16 * 68];           // 17KB padded partial buffer
    const int tid = threadIdx.x, lane = tid & 63, w = tid >> 6;
    const int rg = (int)blockIdx.x >> 4;
    const int cs = (int)blockIdx.x & 15;
    const int row0 = rg * 16, n0 = cs * 64;

    // fill Ws swizzled: byte(r,kb) = r*2048 + (kb ^ ((r&7)<<4))
    for (int idx = tid; idx < 64 * 128; idx += 256) {
        int r = idx >> 7, kb = (idx & 127) * 16;
        s16x8 v = *(const s16x8*)(WbotT + (size_t)(n0 + r) * H_ + (idx & 127) * 8);
        *(s16x8*)((char*)Ws + r * 2048 + (kb ^ ((r & 7) << 4))) = v;
    }
    __syncthreads();

    const int l15 = lane & 15, l4 = lane >> 4;
    const int hrow = row0 + l15;              // h row this thread reads AND writes
    const int col0 = n0 + w * 16 + l4 * 4;    // 4 consecutive output cols (reduce phase)
    const unsigned* fp = flags + rg * 64 + lane;      // poll: lane = slice*4+wave
    unsigned* myflag = flags + rg * 64 + cs * 4 + w;  // publish

    // swizzled Ws read bases: row = cg*16+l15, kbyte = l4*16 + (8w+j)*64
    // addr = row*2048 + (l4*16 ^ ((l15&3)<<4)) + ((8w+j) ^ ((l15>>2)&1))*64
    const int b6 = (l15 >> 2) & 1;
    const char* wsRow = (const char*)Ws + l15 * 2048 + ((l4 * 16) ^ ((l15 & 3) << 4)) + w * 512;
    const char* wE = wsRow + b6 * 64;   // even j
    const char* wO = wsRow - b6 * 64;   // odd j

    p4_t pvA, pvB;
    pvA = pre_ld(pre + (size_t)hrow * H_ + col0);   // pre[t=0]
    asm volatile("s_waitcnt vmcnt(0)" ::: "memory");

    for (int t = 0; t < T_; t += 2) {
        STEP(t,     pvA, pvB);
        STEP(t + 1, pvB, pvA);
    }
}

// ---------- launch ----------
extern "C" void kernel_launch(void* const* d_in, const int* in_sizes, int n_in,
                              void* d_out, int out_size, void* d_ws, size_t ws_size,
                              hipStream_t stream)
{
    const float* x     = (const float*)d_in[0];
    const float* W_in  = (const float*)d_in[1];
    const float* b_in  = (const float*)d_in[2];
    const float* W_h   = (const float*)d_in[3];
    const float* b_h   = (const float*)d_in[4];
    const float* W_out = (const float*)d_in[5];
    const float* b_out = (const float*)d_in[6];
    float* out = (float*)d_out;

    char* ws = (char*)d_ws;
    size_t off = 0;
    auto alloc = [&](size_t bytes) { void* p = ws + off; off += (bytes + 255) & ~(size_t)255; return p; };

    unsigned short* Xb    = (unsigned short*)alloc((size_t)MT_ * I_ * 2);
    unsigned short* WinT  = (unsigned short*)alloc((size_t)H_ * I_ * 2);
    unsigned short* WtopT = (unsigned short*)alloc((size_t)H_ * H_ * 2);
    unsigned short* WbotT = (unsigned short*)alloc((size_t)H_ * H_ * 2);
    unsigned short* WoutT = (unsigned short*)alloc((size_t)O_ * H_ * 2);
    unsigned short* Abuf  = (unsigned short*)alloc((size_t)MT_ * H_ * 2);
    unsigned short* hbuf  = (unsigned short*)alloc((size_t)2 * B_ * H_ * 2);
    unsigned*       flags = (unsigned*)alloc(RG_ * 64 * sizeof(unsigned));
    void* pre = ws + off;
    const bool pre_f32 = (off + (size_t)MT_ * H_ * 4) <= ws_size;

    hipMemsetAsync(hbuf, 0, (size_t)2 * B_ * H_ * 2, stream);
    hipMemsetAsync(flags, 0, RG_ * 64 * sizeof(unsigned), stream);

    cvt_x<<<2048, 256, 0, stream>>>(x, Xb, MT_ * I_);
    dim3 tb(32, 8);
    cvt_t<<<dim3(H_ / 32, I_ / 32), tb, 0, stream>>>(W_in,  WinT,  I_, H_, 0);
    cvt_t<<<dim3(H_ / 32, H_ / 32), tb, 0, stream>>>(W_h,   WtopT, H_, H_, 0);
    cvt_t<<<dim3(H_ / 32, H_ / 32), tb, 0, stream>>>(W_h,   WbotT, H_, H_, H_);
    cvt_t<<<dim3(O_ / 32, H_ / 32), tb, 0, stream>>>(W_out, WoutT, H_, O_, 0);

    // GEMM1: A = lrelu(X @ W_in + b_in)   [MT, H] bf16
    gemm_bf16<unsigned short, true, false>
        <<<dim3(MT_ / 128, H_ / 128), 256, 0, stream>>>(Xb, WinT, b_in, Abuf, MT_, I_, H_);

    // GEMM2: pre = A @ Wtop + b_h   written t-major [T][B][H]
    if (pre_f32) {
        gemm_bf16<float, false, true>
            <<<dim3(MT_ / 128, H_ / 128), 256, 0, stream>>>(Abuf, WtopT, b_h, (float*)pre, MT_, H_, H_);
        rnn_scan8<float><<<RG_ * CS_, 256, 0, stream>>>(WbotT, (const float*)pre, hbuf, flags);
    } else {
        gemm_bf16<unsigned short, false, true>
            <<<dim3(MT_ / 128, H_ / 128), 256, 0, stream>>>(Abuf, WtopT, b_h, (unsigned short*)pre, MT_, H_, H_);
        rnn_scan8<unsigned short><<<RG_ * CS_, 256, 0, stream>>>(WbotT, (const unsigned short*)pre, hbuf, flags);
    }

    // final: out = h_final @ W_out + b_out   (h_final = hbuf[0] since T even)
    gemm_bf16<float, false, false>
        <<<dim3(1, O_ / 128), 256, 0, stream>>>(hbuf, WoutT, b_out, out, B_, H_, O_);
}

// Round 9
// 4957.811 us; speedup vs baseline: 1.9477x; 1.2284x over previous
//
#include <hip/hip_runtime.h>
#include <hip/hip_bf16.h>

// ---------- types ----------
typedef __attribute__((ext_vector_type(8))) short  s16x8;
typedef __attribute__((ext_vector_type(4))) float  f32x4;
typedef __attribute__((ext_vector_type(4))) unsigned short u16x4;
typedef __attribute__((ext_vector_type(4))) unsigned int   u32x4;

#define B_  64
#define T_  1024
#define I_  512
#define H_  1024
#define O_  512
#define MT_ 65536   // B_*T_

// scan decomposition: 4 row-groups x 16 col-slices; 4 waves split K
#define RG_   4
#define CS_   16

// ---------- helpers ----------
__device__ __forceinline__ unsigned short f2bf(float f) {
    unsigned u = __builtin_bit_cast(unsigned, f);
    u += 0x7FFFu + ((u >> 16) & 1u);
    return (unsigned short)(u >> 16);
}
__device__ __forceinline__ float bf2f(unsigned short h) {
    return __builtin_bit_cast(float, ((unsigned)h) << 16);
}
__device__ __forceinline__ void store_out(float* p, float v) { *p = v; }
__device__ __forceinline__ void store_out(unsigned short* p, float v) { *p = f2bf(v); }
__device__ __forceinline__ float to_f32(float v) { return v; }
__device__ __forceinline__ float to_f32(unsigned short v) { return bf2f(v); }

template<typename T> struct pre4;
template<> struct pre4<float>          { using t = f32x4; };
template<> struct pre4<unsigned short> { using t = u16x4; };

// async pre loads (plain cached), pinned in issue order by asm volatile
__device__ __forceinline__ f32x4 pre_ld(const float* p) {
    f32x4 d; asm volatile("global_load_dwordx4 %0, %1, off" : "=v"(d) : "v"(p)); return d;
}
__device__ __forceinline__ u16x4 pre_ld(const unsigned short* p) {
    u16x4 d; asm volatile("global_load_dwordx2 %0, %1, off" : "=v"(d) : "v"(p)); return d;
}

#define GL2LDS16(gp, lp) __builtin_amdgcn_global_load_lds( \
    (const __attribute__((address_space(1))) void*)(gp),   \
    (__attribute__((address_space(3))) void*)(lp), 16, 0, 0)

// ---------- conversion kernels ----------
__global__ void cvt_x(const float* __restrict__ src, unsigned short* __restrict__ dst, int n) {
    int stride = gridDim.x * blockDim.x * 4;
    for (int i = (blockIdx.x * blockDim.x + threadIdx.x) * 4; i < n; i += stride) {
        const float4 v = *(const float4*)(src + i);
        u16x4 o;
        o.x = f2bf(v.x); o.y = f2bf(v.y); o.z = f2bf(v.z); o.w = f2bf(v.w);
        *(u16x4*)(dst + i) = o;
    }
}

// dst[c][r] = bf16(src[row_off + r][c]);  src region [SR,SC] row-major -> dst [SC,SR]
__global__ void cvt_t(const float* __restrict__ src, unsigned short* __restrict__ dst,
                      int SR, int SC, int row_off) {
    __shared__ unsigned short tile[32][33];
    int c0 = blockIdx.x * 32, r0 = blockIdx.y * 32;
    int tx = threadIdx.x, ty = threadIdx.y;
    #pragma unroll
    for (int i = 0; i < 32; i += 8)
        tile[ty + i][tx] = f2bf(src[(size_t)(row_off + r0 + ty + i) * SC + c0 + tx]);
    __syncthreads();
    #pragma unroll
    for (int i = 0; i < 32; i += 8)
        dst[(size_t)(c0 + ty + i) * SR + r0 + tx] = tile[tx][ty + i];
}

// strip tags from final h (slot 0): dst bf16 = src u32 >> 16. sc0sc1 loads
// (scan stores bypassed L2; avoid stale plain-path reads of e.g. memset zeros).
__global__ void strip_h(const unsigned* __restrict__ src, unsigned short* __restrict__ dst) {
    int i = blockIdx.x * blockDim.x + threadIdx.x;   // 16384 uint4s
    const unsigned* p = src + i * 4;
    u32x4 v;
    asm volatile("global_load_dwordx4 %0, %1, off sc0 sc1" : "=v"(v) : "v"(p) : "memory");
    asm volatile("s_waitcnt vmcnt(0)" ::: "memory");
    u16x4 o;
    o.x = (unsigned short)(v.x >> 16); o.y = (unsigned short)(v.y >> 16);
    o.z = (unsigned short)(v.z >> 16); o.w = (unsigned short)(v.w >> 16);
    *(u16x4*)(dst + i * 4) = o;
}

// ---------- generic bf16 MFMA GEMM: C[M,N] = act(A[M,K] @ BT[N,K]^T + bias) ----------
template<typename OutT, bool LRELU, bool SCATTER>
__global__ __launch_bounds__(256)
void gemm_bf16(const unsigned short* __restrict__ A,
               const unsigned short* __restrict__ BT,
               const float* __restrict__ bias,
               OutT* __restrict__ C, int M, int K, int N)
{
    __shared__ unsigned short As[4096]; // [128][32]
    __shared__ unsigned short Bs[4096]; // [128][32]
    const int tid = threadIdx.x, lane = tid & 63, wid = tid >> 6;
    const int wr = wid >> 1, wc = wid & 1;
    const int m0 = blockIdx.x * 128, n0 = blockIdx.y * 128;

    f32x4 acc[4][4] = {};

    const int c = wid * 2;
    const int srow = lane >> 2;
    const int scol = (lane & 3) * 8;
    const unsigned short* Ag0 = A  + (size_t)(m0 + c * 16 + srow) * K + scol;
    const unsigned short* Ag1 = A  + (size_t)(m0 + c * 16 + 16 + srow) * K + scol;
    const unsigned short* Bg0 = BT + (size_t)(n0 + c * 16 + srow) * K + scol;
    const unsigned short* Bg1 = BT + (size_t)(n0 + c * 16 + 16 + srow) * K + scol;

    for (int k0 = 0; k0 < K; k0 += 32) {
        __syncthreads();
        GL2LDS16(Ag0 + k0, As + c * 512);
        GL2LDS16(Ag1 + k0, As + (c + 1) * 512);
        GL2LDS16(Bg0 + k0, Bs + c * 512);
        GL2LDS16(Bg1 + k0, Bs + (c + 1) * 512);
        __syncthreads();

        s16x8 af[4], bfr[4];
        #pragma unroll
        for (int i = 0; i < 4; i++)
            af[i] = *(const s16x8*)(As + (wr * 64 + i * 16 + (lane & 15)) * 32 + (lane >> 4) * 8);
        #pragma unroll
        for (int j = 0; j < 4; j++)
            bfr[j] = *(const s16x8*)(Bs + (wc * 64 + j * 16 + (lane & 15)) * 32 + (lane >> 4) * 8);
        #pragma unroll
        for (int i = 0; i < 4; i++)
            #pragma unroll
            for (int j = 0; j < 4; j++)
                acc[i][j] = __builtin_amdgcn_mfma_f32_16x16x32_bf16(af[i], bfr[j], acc[i][j], 0, 0, 0);
    }

    #pragma unroll
    for (int j = 0; j < 4; j++) {
        const int n = n0 + wc * 64 + j * 16 + (lane & 15);
        const float bv = bias[n];
        #pragma unroll
        for (int i = 0; i < 4; i++) {
            #pragma unroll
            for (int r = 0; r < 4; r++) {
                const int m = m0 + wr * 64 + i * 16 + (lane >> 4) * 4 + r;
                if (m < M) {
                    float v = acc[i][j][r] + bv;
                    if (LRELU) v = v >= 0.f ? v : 0.01f * v;
                    size_t row = SCATTER ? (size_t)((m & (T_ - 1)) * B_ + (m >> 10)) : (size_t)m;
                    store_out(&C[row * N + n], v);
                }
            }
        }
    }
}

// ---------- scan v9: self-validating tagged data — one L3 round trip per step ----
// 64 blocks (4 rg x 16 cs) x 256 thr. h stored as u32 = (bf16<<16)|step_tag in a
// ping-pong u32 buffer (slot = tag&1). Producer: fire tagged dwordx4, NO ack, NO
// flag. Consumer: burst-load k-quarter (16 dwordx4 sc0sc1), one vmcnt(0), tag
// check (XOR/OR), retry. Tag+value in one u32 => torn visibility self-validates.
// K-split MFMA + LDS reduce as r8; pbuf guarded by two cheap s_barriers.

#define TAGLD(d, OFFSTR) asm volatile( \
    "global_load_dwordx4 %0, %1, off offset:" OFFSTR " sc0 sc1" \
    : "=v"(d) : "v"(tbase))

#define STEP(S, PVUSE, PVFILL) do { \
    const char* hc32 = (const char*)hbuf32 + (((S) & 1) << 18); \
    char*       hn32 = (char*)hbuf32 + ((((S) + 1) & 1) << 18); \
    const unsigned tagS = (unsigned)(S); \
    const char* tbase = hc32 + hrow * 4096 + w * 1024 + l4 * 32; \
    u32x4 tv[16]; \
    for (;;) { \
        TAGLD(tv[0],  "0");   TAGLD(tv[1],  "16");  TAGLD(tv[2],  "128"); TAGLD(tv[3],  "144"); \
        TAGLD(tv[4],  "256"); TAGLD(tv[5],  "272"); TAGLD(tv[6],  "384"); TAGLD(tv[7],  "400"); \
        TAGLD(tv[8],  "512"); TAGLD(tv[9],  "528"); TAGLD(tv[10], "640"); TAGLD(tv[11], "656"); \
        TAGLD(tv[12], "768"); TAGLD(tv[13], "784"); TAGLD(tv[14], "896"); TAGLD(tv[15], "912"); \
        asm volatile("s_waitcnt vmcnt(0)" ::: "memory"); \
        __builtin_amdgcn_sched_barrier(0); \
        unsigned d_ = 0; \
        _Pragma("unroll") \
        for (int i = 0; i < 16; i++) \
            d_ |= (tv[i].x ^ tagS) | (tv[i].y ^ tagS) | (tv[i].z ^ tagS) | (tv[i].w ^ tagS); \
        if (__all((int)((d_ & 0xFFFFu) == 0u))) break; \
    } \
    { const int sn = ((S) + 1 < T_) ? (S) + 1 : (S); \
      PVFILL = pre_ld(pre + ((size_t)sn * B_ + hrow) * H_ + col0); } \
    f32x4 ac[4] = {}; \
    _Pragma("unroll") \
    for (int cg = 0; cg < 4; ++cg) { \
        const char* pE = wE + cg * 32768; \
        const char* pO = wO + cg * 32768; \
        _Pragma("unroll") \
        for (int j = 0; j < 8; ++j) { \
            u32x4 a_ = tv[2 * j], b_ = tv[2 * j + 1]; \
            u32x4 f_; \
            f_.x = (a_.x >> 16) | (a_.y & 0xFFFF0000u); \
            f_.y = (a_.z >> 16) | (a_.w & 0xFFFF0000u); \
            f_.z = (b_.x >> 16) | (b_.y & 0xFFFF0000u); \
            f_.w = (b_.z >> 16) | (b_.w & 0xFFFF0000u); \
            s16x8 hfrag = __builtin_bit_cast(s16x8, f_); \
            s16x8 g = *(const s16x8*)(((j & 1) ? pO : pE) + j * 64); \
            ac[cg] = __builtin_amdgcn_mfma_f32_16x16x32_bf16(g, hfrag, ac[cg], 0, 0, 0); \
        } \
    } \
    { float* pw_ = pbuf + (w * 16 + l15) * 68 + l4 * 4; \
      *(f32x4*)(pw_ +  0) = ac[0]; \
      *(f32x4*)(pw_ + 16) = ac[1]; \
      *(f32x4*)(pw_ + 32) = ac[2]; \
      *(f32x4*)(pw_ + 48) = ac[3]; } \
    asm volatile("s_waitcnt lgkmcnt(0)" ::: "memory"); \
    __builtin_amdgcn_s_barrier(); \
    asm volatile("" ::: "memory"); \
    { const float* pr_ = pbuf + l15 * 68 + w * 16 + l4 * 4; \
      f32x4 s0 = *(const f32x4*)(pr_); \
      f32x4 s1 = *(const f32x4*)(pr_ + 1088); \
      f32x4 s2 = *(const f32x4*)(pr_ + 2176); \
      f32x4 s3 = *(const f32x4*)(pr_ + 3264); \
      f32x4 sm = (s0 + s1) + (s2 + s3); \
      u32x4 ow; \
      _Pragma("unroll") \
      for (int r = 0; r < 4; r++) { \
          float v = sm[r] + to_f32(PVUSE[r]); \
          v = v >= 0.f ? v : 0.01f * v; \
          ow[r] = ((unsigned)f2bf(v) << 16) | (tagS + 1u); \
      } \
      char* sp = hn32 + hrow * 4096 + col0 * 4; \
      asm volatile("global_store_dwordx4 %0, %1, off sc0 sc1" \
                   :: "v"(sp), "v"(ow) : "memory"); } \
    asm volatile("s_barrier" ::: "memory"); \
  } while (0)

template<typename PreT>
__global__ __launch_bounds__(256, 1)
void rnn_scan9(const unsigned short* __restrict__ WbotT,
               const PreT* __restrict__ pre,      // [T][B][H] t-major
               unsigned* __restrict__ hbuf32)     // [2][B][H] tagged u32
{
    using p4_t = typename pre4<PreT>::t;
    __shared__ unsigned short Ws[64 * 1024];      // 128KiB, XOR-swizzled rows
    __shared__ float pbuf[4 * 16 * 68];           // 17KB padded partial buffer
    const int tid = threadIdx.x, lane = tid & 63, w = tid >> 6;
    const int rg = (int)blockIdx.x >> 4;
    const int cs = (int)blockIdx.x & 15;
    const int row0 = rg * 16, n0 = cs * 64;

    // fill Ws swizzled: byte(r,kb) = r*2048 + (kb ^ ((r&7)<<4))
    for (int idx = tid; idx < 64 * 128; idx += 256) {
        int r = idx >> 7, kb = (idx & 127) * 16;
        s16x8 v = *(const s16x8*)(WbotT + (size_t)(n0 + r) * H_ + (idx & 127) * 8);
        *(s16x8*)((char*)Ws + r * 2048 + (kb ^ ((r & 7) << 4))) = v;
    }
    __syncthreads();

    const int l15 = lane & 15, l4 = lane >> 4;
    const int hrow = row0 + l15;              // h row this thread reads AND writes
    const int col0 = n0 + w * 16 + l4 * 4;    // 4 consecutive output cols (reduce phase)

    // swizzled Ws read bases: row = cg*16+l15, kbyte = l4*16 + (8w+j)*64
    const int b6 = (l15 >> 2) & 1;
    const char* wsRow = (const char*)Ws + l15 * 2048 + ((l4 * 16) ^ ((l15 & 3) << 4)) + w * 512;
    const char* wE = wsRow + b6 * 64;   // even j
    const char* wO = wsRow - b6 * 64;   // odd j

    p4_t pvA, pvB;
    pvA = pre_ld(pre + (size_t)hrow * H_ + col0);   // pre[t=0]
    asm volatile("s_waitcnt vmcnt(0)" ::: "memory");

    for (int t = 0; t < T_; t += 2) {
        STEP(t,     pvA, pvB);
        STEP(t + 1, pvB, pvA);
    }
}

// ---------- launch ----------
extern "C" void kernel_launch(void* const* d_in, const int* in_sizes, int n_in,
                              void* d_out, int out_size, void* d_ws, size_t ws_size,
                              hipStream_t stream)
{
    const float* x     = (const float*)d_in[0];
    const float* W_in  = (const float*)d_in[1];
    const float* b_in  = (const float*)d_in[2];
    const float* W_h   = (const float*)d_in[3];
    const float* b_h   = (const float*)d_in[4];
    const float* W_out = (const float*)d_in[5];
    const float* b_out = (const float*)d_in[6];
    float* out = (float*)d_out;

    char* ws = (char*)d_ws;
    size_t off = 0;
    auto alloc = [&](size_t bytes) { void* p = ws + off; off += (bytes + 255) & ~(size_t)255; return p; };

    unsigned short* Xb    = (unsigned short*)alloc((size_t)MT_ * I_ * 2);
    unsigned short* WinT  = (unsigned short*)alloc((size_t)H_ * I_ * 2);
    unsigned short* WtopT = (unsigned short*)alloc((size_t)H_ * H_ * 2);
    unsigned short* WbotT = (unsigned short*)alloc((size_t)H_ * H_ * 2);
    unsigned short* WoutT = (unsigned short*)alloc((size_t)O_ * H_ * 2);
    unsigned short* Abuf  = (unsigned short*)alloc((size_t)MT_ * H_ * 2);
    unsigned*       hbuf32 = (unsigned*)alloc((size_t)2 * B_ * H_ * 4);   // tagged ping-pong
    unsigned short* hfin  = (unsigned short*)alloc((size_t)B_ * H_ * 2);  // stripped h_T
    void* pre = ws + off;
    const bool pre_f32 = (off + (size_t)MT_ * H_ * 4) <= ws_size;

    // memset 0: slot0 tag0 == step-0 tag (h0 = 0) ✓; slot1 tag0 != odd tags ✓
    hipMemsetAsync(hbuf32, 0, (size_t)2 * B_ * H_ * 4, stream);

    cvt_x<<<2048, 256, 0, stream>>>(x, Xb, MT_ * I_);
    dim3 tb(32, 8);
    cvt_t<<<dim3(H_ / 32, I_ / 32), tb, 0, stream>>>(W_in,  WinT,  I_, H_, 0);
    cvt_t<<<dim3(H_ / 32, H_ / 32), tb, 0, stream>>>(W_h,   WtopT, H_, H_, 0);
    cvt_t<<<dim3(H_ / 32, H_ / 32), tb, 0, stream>>>(W_h,   WbotT, H_, H_, H_);
    cvt_t<<<dim3(O_ / 32, H_ / 32), tb, 0, stream>>>(W_out, WoutT, H_, O_, 0);

    // GEMM1: A = lrelu(X @ W_in + b_in)   [MT, H] bf16
    gemm_bf16<unsigned short, true, false>
        <<<dim3(MT_ / 128, H_ / 128), 256, 0, stream>>>(Xb, WinT, b_in, Abuf, MT_, I_, H_);

    // GEMM2: pre = A @ Wtop + b_h   written t-major [T][B][H]
    if (pre_f32) {
        gemm_bf16<float, false, true>
            <<<dim3(MT_ / 128, H_ / 128), 256, 0, stream>>>(Abuf, WtopT, b_h, (float*)pre, MT_, H_, H_);
        rnn_scan9<float><<<RG_ * CS_, 256, 0, stream>>>(WbotT, (const float*)pre, hbuf32);
    } else {
        gemm_bf16<unsigned short, false, true>
            <<<dim3(MT_ / 128, H_ / 128), 256, 0, stream>>>(Abuf, WtopT, b_h, (unsigned short*)pre, MT_, H_, H_);
        rnn_scan9<unsigned short><<<RG_ * CS_, 256, 0, stream>>>(WbotT, (const unsigned short*)pre, hbuf32);
    }

    // h_T lives in slot 0 (tag 1024); strip tags then final GEMM
    strip_h<<<64, 256, 0, stream>>>(hbuf32, hfin);
    gemm_bf16<float, false, false>
        <<<dim3(1, O_ / 128), 256, 0, stream>>>(hfin, WoutT, b_out, out, B_, H_, O_);
}